// Round 1
// baseline (37225.314 us; speedup 1.0000x reference)
//
#include <hip/hip_runtime.h>
#include <hip/hip_fp16.h>

typedef _Float16 h2v __attribute__((ext_vector_type(2)));

__device__ __forceinline__ float fdot2(unsigned int a, unsigned int b, float c) {
    return __builtin_amdgcn_fdot2(__builtin_bit_cast(h2v, a),
                                  __builtin_bit_cast(h2v, b), c, false);
}

#define SCOPE_AGENT __HIP_MEMORY_SCOPE_AGENT

// ---------------- fp32 -> fp16 convert (vectorized x4) ----------------
__global__ __launch_bounds__(256) void k_f2h(const float* __restrict__ src,
                                             __half* __restrict__ dst, int n4) {
    int i = blockIdx.x * 256 + threadIdx.x;
    if (i >= n4) return;
    float4 v = ((const float4*)src)[i];
    union { __half2 h[2]; uint2 u; } o;
    o.h[0] = __halves2half2(__float2half_rn(v.x), __float2half_rn(v.y));
    o.h[1] = __halves2half2(__float2half_rn(v.z), __float2half_rn(v.w));
    ((uint2*)dst)[i] = o.u;
}

__global__ __launch_bounds__(256) void k_bias(const float* __restrict__ a,
                                              const float* __restrict__ b,
                                              float* __restrict__ o) {
    int i = blockIdx.x * 256 + threadIdx.x;
    if (i < 4096) o[i] = a[i] + b[i];
}

// ---------------- x_gates GEMM: C[8192][4096] = A[8192][1024] @ B[4096][1024]^T + bias ----
// fp16 inputs, fp32 accumulate via v_dot2_f32_f16. 128x128 tile, BK=32 halfs.
__global__ __launch_bounds__(256) void k_gemm_xg(const __half* __restrict__ A,
                                                 const __half* __restrict__ B,
                                                 const float* __restrict__ bias,
                                                 __half* __restrict__ C) {
    __shared__ unsigned int As[128][20];   // half2 elements, padded stride 20 dwords
    __shared__ unsigned int Bs[128][20];
    const int tid = threadIdx.x;
    const int tx = tid & 15, ty = tid >> 4;
    const int m0 = blockIdx.x * 128, n0 = blockIdx.y * 128;
    float acc[8][8];
#pragma unroll
    for (int i = 0; i < 8; ++i)
#pragma unroll
        for (int j = 0; j < 8; ++j) acc[i][j] = 0.f;
    const unsigned int* Ag = (const unsigned int*)(A + (size_t)m0 * 1024);
    const unsigned int* Bg = (const unsigned int*)(B + (size_t)n0 * 1024);
    for (int k0 = 0; k0 < 512; k0 += 16) {   // k0 in uint(=half2) units
        __syncthreads();
#pragma unroll
        for (int j = 0; j < 2; ++j) {
            int qd = j * 256 + tid;          // 512 quads of 16B
            int row = qd >> 2;
            int c4 = (qd & 3) << 2;
            uint4 va = *(const uint4*)(Ag + (size_t)row * 512 + k0 + c4);
            uint4 vb = *(const uint4*)(Bg + (size_t)row * 512 + k0 + c4);
            *(uint4*)&As[row][c4] = va;
            *(uint4*)&Bs[row][c4] = vb;
        }
        __syncthreads();
#pragma unroll
        for (int k2 = 0; k2 < 16; k2 += 2) {
            unsigned int a0[8], a1[8], b0[8], b1[8];
#pragma unroll
            for (int i = 0; i < 8; ++i) {
                uint2 v = *(const uint2*)&As[ty + 16 * i][k2];
                a0[i] = v.x; a1[i] = v.y;
            }
#pragma unroll
            for (int j = 0; j < 8; ++j) {
                uint2 v = *(const uint2*)&Bs[tx + 16 * j][k2];
                b0[j] = v.x; b1[j] = v.y;
            }
#pragma unroll
            for (int i = 0; i < 8; ++i)
#pragma unroll
                for (int j = 0; j < 8; ++j) {
                    acc[i][j] = fdot2(a0[i], b0[j], acc[i][j]);
                    acc[i][j] = fdot2(a1[i], b1[j], acc[i][j]);
                }
        }
    }
#pragma unroll
    for (int i = 0; i < 8; ++i) {
        int row = m0 + ty + 16 * i;
#pragma unroll
        for (int j = 0; j < 8; ++j) {
            int col = n0 + tx + 16 * j;
            C[(size_t)row * 4096 + col] = __float2half_rn(acc[i][j] + bias[col]);
        }
    }
}

// ---------------- persistent LSTM recurrence ----------------
// 128 blocks x 256 threads. Block b owns hidden units [8b, 8b+8): local row r in [0,32),
// global gate row = (r>>3)*1024 + 8b + (r&7). W_hh fp16 in LDS (64KB), XOR-swizzled.
// h broadcast via double-buffered global half2 array + per-block generation flags
// (agent-scope atomics; __syncthreads drains stores before the flag release).
__global__ __launch_bounds__(256) void k_lstm(const __half* __restrict__ Whh,
                                              const __half* __restrict__ xg,
                                              unsigned int* hbuf,   // [2][1024] uints (half2)
                                              int* flags) {         // [128*32]
    __shared__ uint4 Wl[32][128];          // 64KB, Wl[r][k8 ^ (r&7)]
    __shared__ unsigned int hs[512];       // staged h (half2)
    __shared__ float red[32][9];
    __shared__ float gbuf[32];
    __shared__ float hh[8];
    __shared__ float cst[8];
    const int tid = threadIdx.x;
    const int b = blockIdx.x;
#pragma unroll
    for (int i = 0; i < 16; ++i) {
        int qd = i * 256 + tid;            // 4096 quads
        int r = qd >> 7, k8 = qd & 127;
        int grow = ((r >> 3) << 10) + b * 8 + (r & 7);
        uint4 v = *(const uint4*)(Whh + (size_t)grow * 1024 + k8 * 8);
        Wl[r][k8 ^ (r & 7)] = v;
    }
    if (tid < 8) cst[tid] = 0.f;
    const int r = tid & 31, q = tid >> 5;
    const int xcol = ((r >> 3) << 10) + b * 8 + (r & 7);
    __syncthreads();

    for (int t = 0; t < 8192; ++t) {
        // prefetch this step's x_gates (independent of h)
        float xv = 0.f;
        if (tid < 32) xv = __half2float(xg[(size_t)t * 4096 + xcol]);
        // wait for all blocks to have published h(t-1)
        if (t > 0 && tid < 128) {
            while (__hip_atomic_load(&flags[tid * 32], __ATOMIC_RELAXED, SCOPE_AGENT) < t) { }
        }
        __syncthreads();                   // A: poll done; also fences prev-step hs reads
        const unsigned int* hsrc = hbuf + ((t + 1) & 1) * 1024;   // buffer (t-1)&1
        unsigned int hv0 = __hip_atomic_load(&hsrc[tid],       __ATOMIC_RELAXED, SCOPE_AGENT);
        unsigned int hv1 = __hip_atomic_load(&hsrc[tid + 256], __ATOMIC_RELAXED, SCOPE_AGENT);
        hs[tid] = hv0; hs[tid + 256] = hv1;
        __syncthreads();                   // B: h staged
        float acc = 0.f;
#pragma unroll
        for (int i = 0; i < 16; ++i) {
            int k8 = q * 16 + i;
            uint4 w = Wl[r][k8 ^ (r & 7)];
            uint4 h4 = *(const uint4*)&hs[k8 << 2];
            acc = fdot2(w.x, h4.x, acc);
            acc = fdot2(w.y, h4.y, acc);
            acc = fdot2(w.z, h4.z, acc);
            acc = fdot2(w.w, h4.w, acc);
        }
        red[r][q] = acc;
        __syncthreads();                   // C: partials ready
        if (tid < 32) {
            float g = xv;
#pragma unroll
            for (int j = 0; j < 8; ++j) g += red[tid][j];
            gbuf[tid] = g;
        }
        __syncthreads();                   // D: gates ready
        if (tid < 8) {
            float gi = 1.f / (1.f + __expf(-gbuf[tid]));
            float gf = 1.f / (1.f + __expf(-gbuf[8 + tid]));
            float gg = tanhf(gbuf[16 + tid]);
            float go = 1.f / (1.f + __expf(-gbuf[24 + tid]));
            float c = gf * cst[tid] + gi * gg;
            cst[tid] = c;
            hh[tid] = go * tanhf(c);
        }
        __syncthreads();                   // E: h slice ready
        if (tid < 4) {
            union { __half2 h; unsigned int u; } pk;
            pk.h = __halves2half2(__float2half_rn(hh[2 * tid]),
                                  __float2half_rn(hh[2 * tid + 1]));
            __hip_atomic_store(&hbuf[(t & 1) * 1024 + b * 4 + tid], pk.u,
                               __ATOMIC_RELEASE, SCOPE_AGENT);
        }
        __syncthreads();                   // F: drains h stores (vmcnt0 before barrier)
        if (tid == 0)
            __hip_atomic_store(&flags[b * 32], t + 1, __ATOMIC_RELEASE, SCOPE_AGENT);
    }
}

// ---------------- final projection: out = h_final @ W_out^T + b_out ----------------
__global__ __launch_bounds__(256) void k_proj(const unsigned int* __restrict__ hfin,
                                              const float* __restrict__ Wout,
                                              const float* __restrict__ bout,
                                              float* __restrict__ out) {
    __shared__ float red[256];
    const int o = blockIdx.x, tid = threadIdx.x;
    const float* wr = Wout + (size_t)o * 1024;
    float acc = 0.f;
#pragma unroll
    for (int j = 0; j < 2; ++j) {
        int k2 = j * 256 + tid;
        union { unsigned int u; __half2 h; } v; v.u = hfin[k2];
        float lo = __half2float(__low2half(v.h));
        float hi = __half2float(__high2half(v.h));
        acc += lo * wr[2 * k2] + hi * wr[2 * k2 + 1];
    }
    red[tid] = acc;
    __syncthreads();
    for (int s = 128; s > 0; s >>= 1) {
        if (tid < s) red[tid] += red[tid + s];
        __syncthreads();
    }
    if (tid == 0) out[o] = red[0] + bout[o];
}

extern "C" void kernel_launch(void* const* d_in, const int* in_sizes, int n_in,
                              void* d_out, int out_size, void* d_ws, size_t ws_size,
                              hipStream_t stream) {
    const float* input_seq = (const float*)d_in[0];
    const float* W_ih = (const float*)d_in[1];
    const float* W_hh = (const float*)d_in[2];
    const float* b_ih = (const float*)d_in[3];
    const float* b_hh = (const float*)d_in[4];
    const float* W_out = (const float*)d_in[5];
    const float* b_out = (const float*)d_in[6];
    float* out = (float*)d_out;

    char* ws = (char*)d_ws;
    unsigned int* hbuf = (unsigned int*)ws;                        // [0, 8KB)
    int* flags = (int*)(ws + 8192);                                // [8KB, 24KB)
    float* bias = (float*)(ws + 24576);                            // [24KB, 40KB)
    __half* Wih_h = (__half*)(ws + 65536);                         // 8MB
    __half* Whh_h = (__half*)(ws + 65536 + (size_t)8 * 1024 * 1024);   // 8MB
    __half* in_h  = (__half*)(ws + 65536 + (size_t)16 * 1024 * 1024);  // 16MB
    __half* xg    = (__half*)(ws + 65536 + (size_t)32 * 1024 * 1024);  // 64MB

    // zero control region (h double-buffer + flags) — required every call for graph replay
    hipMemsetAsync(ws, 0, 24576, stream);

    k_f2h<<<8192, 256, 0, stream>>>(input_seq, in_h, 2 * 1024 * 1024);
    k_f2h<<<4096, 256, 0, stream>>>(W_ih, Wih_h, 1024 * 1024);
    k_f2h<<<4096, 256, 0, stream>>>(W_hh, Whh_h, 1024 * 1024);
    k_bias<<<16, 256, 0, stream>>>(b_ih, b_hh, bias);

    dim3 gg(64, 32);
    k_gemm_xg<<<gg, 256, 0, stream>>>(in_h, Wih_h, bias, xg);

    k_lstm<<<128, 256, 0, stream>>>(Whh_h, xg, hbuf, flags);

    k_proj<<<1024, 256, 0, stream>>>(hbuf + 1024, W_out, b_out, out);
}

// Round 2
// 25426.424 us; speedup vs baseline: 1.4640x; 1.4640x over previous
//
#include <hip/hip_runtime.h>
#include <hip/hip_fp16.h>

typedef _Float16 h2v __attribute__((ext_vector_type(2)));

__device__ __forceinline__ float fdot2(unsigned int a, unsigned int b, float c) {
    return __builtin_amdgcn_fdot2(__builtin_bit_cast(h2v, a),
                                  __builtin_bit_cast(h2v, b), c, false);
}

#define SCOPE_AGENT __HIP_MEMORY_SCOPE_AGENT

// ---------------- fp32 -> fp16 convert (vectorized x4) ----------------
__global__ __launch_bounds__(256) void k_f2h(const float* __restrict__ src,
                                             __half* __restrict__ dst, int n4) {
    int i = blockIdx.x * 256 + threadIdx.x;
    if (i >= n4) return;
    float4 v = ((const float4*)src)[i];
    union { __half2 h[2]; uint2 u; } o;
    o.h[0] = __halves2half2(__float2half_rn(v.x), __float2half_rn(v.y));
    o.h[1] = __halves2half2(__float2half_rn(v.z), __float2half_rn(v.w));
    ((uint2*)dst)[i] = o.u;
}

__global__ __launch_bounds__(256) void k_bias(const float* __restrict__ a,
                                              const float* __restrict__ b,
                                              float* __restrict__ o) {
    int i = blockIdx.x * 256 + threadIdx.x;
    if (i < 4096) o[i] = a[i] + b[i];
}

// ---------------- x_gates GEMM: C[8192][4096] = A[8192][1024] @ B[4096][1024]^T + bias ----
__global__ __launch_bounds__(256) void k_gemm_xg(const __half* __restrict__ A,
                                                 const __half* __restrict__ B,
                                                 const float* __restrict__ bias,
                                                 __half* __restrict__ C) {
    __shared__ unsigned int As[128][20];
    __shared__ unsigned int Bs[128][20];
    const int tid = threadIdx.x;
    const int tx = tid & 15, ty = tid >> 4;
    const int m0 = blockIdx.x * 128, n0 = blockIdx.y * 128;
    float acc[8][8];
#pragma unroll
    for (int i = 0; i < 8; ++i)
#pragma unroll
        for (int j = 0; j < 8; ++j) acc[i][j] = 0.f;
    const unsigned int* Ag = (const unsigned int*)(A + (size_t)m0 * 1024);
    const unsigned int* Bg = (const unsigned int*)(B + (size_t)n0 * 1024);
    for (int k0 = 0; k0 < 512; k0 += 16) {
        __syncthreads();
#pragma unroll
        for (int j = 0; j < 2; ++j) {
            int qd = j * 256 + tid;
            int row = qd >> 2;
            int c4 = (qd & 3) << 2;
            uint4 va = *(const uint4*)(Ag + (size_t)row * 512 + k0 + c4);
            uint4 vb = *(const uint4*)(Bg + (size_t)row * 512 + k0 + c4);
            *(uint4*)&As[row][c4] = va;
            *(uint4*)&Bs[row][c4] = vb;
        }
        __syncthreads();
#pragma unroll
        for (int k2 = 0; k2 < 16; k2 += 2) {
            unsigned int a0[8], a1[8], b0[8], b1[8];
#pragma unroll
            for (int i = 0; i < 8; ++i) {
                uint2 v = *(const uint2*)&As[ty + 16 * i][k2];
                a0[i] = v.x; a1[i] = v.y;
            }
#pragma unroll
            for (int j = 0; j < 8; ++j) {
                uint2 v = *(const uint2*)&Bs[tx + 16 * j][k2];
                b0[j] = v.x; b1[j] = v.y;
            }
#pragma unroll
            for (int i = 0; i < 8; ++i)
#pragma unroll
                for (int j = 0; j < 8; ++j) {
                    acc[i][j] = fdot2(a0[i], b0[j], acc[i][j]);
                    acc[i][j] = fdot2(a1[i], b1[j], acc[i][j]);
                }
        }
    }
#pragma unroll
    for (int i = 0; i < 8; ++i) {
        int row = m0 + ty + 16 * i;
#pragma unroll
        for (int j = 0; j < 8; ++j) {
            int col = n0 + tx + 16 * j;
            C[(size_t)row * 4096 + col] = __float2half_rn(acc[i][j] + bias[col]);
        }
    }
}

// ---------------- persistent LSTM recurrence ----------------
// 128 blocks x 256 threads (4 waves). Block b owns hidden units [8b,8b+8);
// wave w owns units {8b+2w, 8b+2w+1} x 4 gates = 8 gate rows, end-to-end.
// Handshake: one tagged 8B atomic per (block,wave): {tag=t+1 | h2}. Readers
// poll the word itself -> data arrives with the tag, single round trip.
// One __syncthreads per step (h staging); everything else is wave-local
// (shfl_xor reduce, shfl gate gather, c-state in registers).
__global__ __launch_bounds__(256) void k_lstm(const __half* __restrict__ Whh,
                                              const __half* __restrict__ xg,
                                              unsigned long long* pub) { // [2][512]
    __shared__ uint4 Wl[32][128];          // 64KB, Wl[R][k8 ^ (R&7)]
    __shared__ unsigned int hs[2][544];    // h staging, chunk stride 68 dwords
    const int tid = threadIdx.x;
    const int b = blockIdx.x;
    const int w = tid >> 6, lane = tid & 63;
    const int rho = lane >> 3;             // sub-row 0..7: gate=rho&3, unit-local=rho>>2
    const int cc = lane & 7;               // k-chunk 0..7 (128 halfs each)

    // stage W_hh slice into LDS, swizzled
#pragma unroll
    for (int i = 0; i < 16; ++i) {
        int qd = i * 256 + tid;            // 4096 uint4 quads
        int R = qd >> 7, k8 = qd & 127;
        int grow = (R & 3) * 1024 + b * 8 + 2 * (R >> 3) + ((R >> 2) & 1);
        Wl[R][k8 ^ (R & 7)] = *(const uint4*)(Whh + (size_t)grow * 1024 + k8 * 8);
    }
    const int e0 = w * 128 + lane;         // pub entries this lane polls/stages
    const int e1 = e0 + 64;
    const int s0 = (e0 >> 6) * 68 + (e0 & 63);
    const int s1 = (e1 >> 6) * 68 + (e1 & 63);
    const int xcol = (rho & 3) * 1024 + b * 8 + 2 * w + (rho >> 2);
    const int Rme = w * 8 + rho;
    float c_state = 0.f;
    __syncthreads();

    for (int t = 0; t < 8192; ++t) {
        // x_gates prefetch (independent of h; hides under the poll)
        float xv = __half2float(xg[(size_t)t * 4096 + xcol]);
        unsigned int d0 = 0, d1 = 0;
        if (t > 0) {
            unsigned long long* src = pub + (((t - 1) & 1) << 9);
            unsigned long long v0, v1;
            do {
                v0 = __hip_atomic_load(src + e0, __ATOMIC_RELAXED, SCOPE_AGENT);
                v1 = __hip_atomic_load(src + e1, __ATOMIC_RELAXED, SCOPE_AGENT);
            } while ((unsigned)(v0 >> 32) != (unsigned)t ||
                     (unsigned)(v1 >> 32) != (unsigned)t);
            d0 = (unsigned)v0; d1 = (unsigned)v1;
        }
        const int p = t & 1;
        hs[p][s0] = d0;
        hs[p][s1] = d1;
        __syncthreads();                   // the ONLY barrier per step
        float acc = 0.f;
        const unsigned int* hsp = &hs[p][cc * 68];
#pragma unroll
        for (int i = 0; i < 16; ++i) {
            uint4 wv = Wl[Rme][(cc * 16 + i) ^ rho];
            uint4 h4 = *(const uint4*)(hsp + i * 4);
            acc = fdot2(wv.x, h4.x, acc);
            acc = fdot2(wv.y, h4.y, acc);
            acc = fdot2(wv.z, h4.z, acc);
            acc = fdot2(wv.w, h4.w, acc);
        }
        // reduce over k-chunks (lanes differing in bits 0..2)
        acc += __shfl_xor(acc, 1);
        acc += __shfl_xor(acc, 2);
        acc += __shfl_xor(acc, 4);
        acc += xv;
        // gather the 4 gates of this half-wave's unit
        const int base = lane & 32;
        float gi = __shfl(acc, base + 0);
        float gf = __shfl(acc, base + 8);
        float gg = __shfl(acc, base + 16);
        float go = __shfl(acc, base + 24);
        gi = 1.f / (1.f + __expf(-gi));
        gf = 1.f / (1.f + __expf(-gf));
        gg = 2.f / (1.f + __expf(-2.f * gg)) - 1.f;
        go = 1.f / (1.f + __expf(-go));
        c_state = gf * c_state + gi * gg;
        float hval = go * (2.f / (1.f + __expf(-2.f * c_state)) - 1.f);
        float hother = __shfl(hval, 32);   // unit-local 1's h
        if (lane == 0) {
            union { __half2 h; unsigned int u; } pk;
            pk.h = __halves2half2(__float2half_rn(hval), __float2half_rn(hother));
            unsigned long long val =
                ((unsigned long long)(unsigned)(t + 1) << 32) | pk.u;
            __hip_atomic_store(pub + (p << 9) + b * 4 + w, val,
                               __ATOMIC_RELAXED, SCOPE_AGENT);
        }
    }
}

// ---------------- final projection: out = h_final @ W_out^T + b_out ----------------
__global__ __launch_bounds__(256) void k_proj(unsigned long long* __restrict__ hfin,
                                              const float* __restrict__ Wout,
                                              const float* __restrict__ bout,
                                              float* __restrict__ out) {
    __shared__ float red[256];
    const int o = blockIdx.x, tid = threadIdx.x;
    const float* wr = Wout + (size_t)o * 1024;
    float acc = 0.f;
#pragma unroll
    for (int j = 0; j < 2; ++j) {
        int e = j * 256 + tid;
        unsigned long long v = __hip_atomic_load(hfin + e, __ATOMIC_RELAXED, SCOPE_AGENT);
        union { unsigned int u; __half2 h; } pk; pk.u = (unsigned)v;
        acc += __half2float(__low2half(pk.h)) * wr[2 * e] +
               __half2float(__high2half(pk.h)) * wr[2 * e + 1];
    }
    red[tid] = acc;
    __syncthreads();
    for (int s = 128; s > 0; s >>= 1) {
        if (tid < s) red[tid] += red[tid + s];
        __syncthreads();
    }
    if (tid == 0) out[o] = red[0] + bout[o];
}

extern "C" void kernel_launch(void* const* d_in, const int* in_sizes, int n_in,
                              void* d_out, int out_size, void* d_ws, size_t ws_size,
                              hipStream_t stream) {
    const float* input_seq = (const float*)d_in[0];
    const float* W_ih = (const float*)d_in[1];
    const float* W_hh = (const float*)d_in[2];
    const float* b_ih = (const float*)d_in[3];
    const float* b_hh = (const float*)d_in[4];
    const float* W_out = (const float*)d_in[5];
    const float* b_out = (const float*)d_in[6];
    float* out = (float*)d_out;

    char* ws = (char*)d_ws;
    unsigned long long* pub = (unsigned long long*)ws;             // [0, 8KB): [2][512] tagged h
    float* bias = (float*)(ws + 24576);                            // [24KB, 40KB)
    __half* Wih_h = (__half*)(ws + 65536);                         // 8MB
    __half* Whh_h = (__half*)(ws + 65536 + (size_t)8 * 1024 * 1024);   // 8MB
    __half* in_h  = (__half*)(ws + 65536 + (size_t)16 * 1024 * 1024);  // 16MB
    __half* xg    = (__half*)(ws + 65536 + (size_t)32 * 1024 * 1024);  // 64MB

    // clear tags each call (graph replay determinism)
    hipMemsetAsync(ws, 0, 8192, stream);

    k_f2h<<<8192, 256, 0, stream>>>(input_seq, in_h, 2 * 1024 * 1024);
    k_f2h<<<4096, 256, 0, stream>>>(W_ih, Wih_h, 1024 * 1024);
    k_f2h<<<4096, 256, 0, stream>>>(W_hh, Whh_h, 1024 * 1024);
    k_bias<<<16, 256, 0, stream>>>(b_ih, b_hh, bias);

    dim3 gg(64, 32);
    k_gemm_xg<<<gg, 256, 0, stream>>>(in_h, Wih_h, bias, xg);

    k_lstm<<<128, 256, 0, stream>>>(Whh_h, xg, pub);

    k_proj<<<1024, 256, 0, stream>>>(pub + 512, W_out, b_out, out);
}

// Round 3
// 22672.411 us; speedup vs baseline: 1.6419x; 1.1215x over previous
//
#include <hip/hip_runtime.h>
#include <hip/hip_fp16.h>

typedef _Float16 h2v __attribute__((ext_vector_type(2)));

__device__ __forceinline__ float fdot2(unsigned int a, unsigned int b, float c) {
    return __builtin_amdgcn_fdot2(__builtin_bit_cast(h2v, a),
                                  __builtin_bit_cast(h2v, b), c, false);
}

#define SCOPE_AGENT __HIP_MEMORY_SCOPE_AGENT

// ---------------- fp32 -> fp16 convert (vectorized x4) ----------------
__global__ __launch_bounds__(256) void k_f2h(const float* __restrict__ src,
                                             __half* __restrict__ dst, int n4) {
    int i = blockIdx.x * 256 + threadIdx.x;
    if (i >= n4) return;
    float4 v = ((const float4*)src)[i];
    union { __half2 h[2]; uint2 u; } o;
    o.h[0] = __halves2half2(__float2half_rn(v.x), __float2half_rn(v.y));
    o.h[1] = __halves2half2(__float2half_rn(v.z), __float2half_rn(v.w));
    ((uint2*)dst)[i] = o.u;
}

__global__ __launch_bounds__(256) void k_bias(const float* __restrict__ a,
                                              const float* __restrict__ b,
                                              float* __restrict__ o) {
    int i = blockIdx.x * 256 + threadIdx.x;
    if (i < 4096) o[i] = a[i] + b[i];
}

// ---------------- x_gates GEMM: C[8192][4096] = A[8192][1024] @ B[4096][1024]^T + bias ----
__global__ __launch_bounds__(256) void k_gemm_xg(const __half* __restrict__ A,
                                                 const __half* __restrict__ B,
                                                 const float* __restrict__ bias,
                                                 __half* __restrict__ C) {
    __shared__ unsigned int As[128][20];
    __shared__ unsigned int Bs[128][20];
    const int tid = threadIdx.x;
    const int tx = tid & 15, ty = tid >> 4;
    const int m0 = blockIdx.x * 128, n0 = blockIdx.y * 128;
    float acc[8][8];
#pragma unroll
    for (int i = 0; i < 8; ++i)
#pragma unroll
        for (int j = 0; j < 8; ++j) acc[i][j] = 0.f;
    const unsigned int* Ag = (const unsigned int*)(A + (size_t)m0 * 1024);
    const unsigned int* Bg = (const unsigned int*)(B + (size_t)n0 * 1024);
    for (int k0 = 0; k0 < 512; k0 += 16) {
        __syncthreads();
#pragma unroll
        for (int j = 0; j < 2; ++j) {
            int qd = j * 256 + tid;
            int row = qd >> 2;
            int c4 = (qd & 3) << 2;
            uint4 va = *(const uint4*)(Ag + (size_t)row * 512 + k0 + c4);
            uint4 vb = *(const uint4*)(Bg + (size_t)row * 512 + k0 + c4);
            *(uint4*)&As[row][c4] = va;
            *(uint4*)&Bs[row][c4] = vb;
        }
        __syncthreads();
#pragma unroll
        for (int k2 = 0; k2 < 16; k2 += 2) {
            unsigned int a0[8], a1[8], b0[8], b1[8];
#pragma unroll
            for (int i = 0; i < 8; ++i) {
                uint2 v = *(const uint2*)&As[ty + 16 * i][k2];
                a0[i] = v.x; a1[i] = v.y;
            }
#pragma unroll
            for (int j = 0; j < 8; ++j) {
                uint2 v = *(const uint2*)&Bs[tx + 16 * j][k2];
                b0[j] = v.x; b1[j] = v.y;
            }
#pragma unroll
            for (int i = 0; i < 8; ++i)
#pragma unroll
                for (int j = 0; j < 8; ++j) {
                    acc[i][j] = fdot2(a0[i], b0[j], acc[i][j]);
                    acc[i][j] = fdot2(a1[i], b1[j], acc[i][j]);
                }
        }
    }
#pragma unroll
    for (int i = 0; i < 8; ++i) {
        int row = m0 + ty + 16 * i;
#pragma unroll
        for (int j = 0; j < 8; ++j) {
            int col = n0 + tx + 16 * j;
            C[(size_t)row * 4096 + col] = __float2half_rn(acc[i][j] + bias[col]);
        }
    }
}

// ---------------- persistent LSTM recurrence ----------------
// 64 blocks x 512 threads (8 waves). Block b owns hidden units [16b,16b+16);
// wave w owns units {16b+2w, 16b+2w+1} x 4 gates = 8 gate rows.
// W_hh rows live in REGISTERS (16 uint4 = 64 VGPR per lane; lane (rho,cc)
// holds row [gate*1024 + unit], k-chunk cc*128..+127). No LDS weight reads.
// Handshake: one tagged 8B atomic per (block,wave) = 512 entries; each lane
// polls exactly ONE entry with s_sleep backoff. One __syncthreads per step.
__global__ __launch_bounds__(512, 1) void k_lstm(const __half* __restrict__ Whh,
                                                 const __half* __restrict__ xg,
                                                 unsigned long long* pub) { // [2][512]
    __shared__ unsigned int hs[2][544];    // staged h (half2), chunk stride 68
    const int tid = threadIdx.x;
    const int b = blockIdx.x;              // 0..63
    const int w = tid >> 6, lane = tid & 63;
    const int rho = lane >> 3;             // gate = rho&3, unit-local = rho>>2
    const int cc = lane & 7;               // k-chunk (128 halfs)
    const int grow = (rho & 3) * 1024 + b * 16 + 2 * w + (rho >> 2);
    uint4 wr[16];
#pragma unroll
    for (int i = 0; i < 16; ++i)
        wr[i] = *(const uint4*)(Whh + (size_t)grow * 1024 + cc * 128 + i * 8);
    const int soff = (tid >> 6) * 68 + (tid & 63);   // hs slot for entry tid
    float c_state = 0.f;
    __syncthreads();

    for (int t = 0; t < 8192; ++t) {
        // x_gates prefetch (independent of h; hides under the poll)
        float xv = __half2float(xg[(size_t)t * 4096 + grow]);
        unsigned int d = 0;
        if (t > 0) {
            const unsigned long long* src = pub + (((t - 1) & 1) << 9);
            unsigned long long v = __hip_atomic_load(src + tid, __ATOMIC_RELAXED, SCOPE_AGENT);
            while ((unsigned)(v >> 32) != (unsigned)t) {
                __builtin_amdgcn_s_sleep(1);
                v = __hip_atomic_load(src + tid, __ATOMIC_RELAXED, SCOPE_AGENT);
            }
            d = (unsigned)v;
        }
        const int p = t & 1;
        hs[p][soff] = d;
        __syncthreads();                   // the ONLY barrier per step
        float acc = 0.f;
        const unsigned int* hsp = &hs[p][cc * 68];
#pragma unroll
        for (int i = 0; i < 16; ++i) {
            uint4 h4 = *(const uint4*)(hsp + i * 4);
            acc = fdot2(wr[i].x, h4.x, acc);
            acc = fdot2(wr[i].y, h4.y, acc);
            acc = fdot2(wr[i].z, h4.z, acc);
            acc = fdot2(wr[i].w, h4.w, acc);
        }
        // reduce over k-chunks (lane bits 0..2)
        acc += __shfl_xor(acc, 1);
        acc += __shfl_xor(acc, 2);
        acc += __shfl_xor(acc, 4);
        acc += xv;
        // gather the 4 gates of this half-wave's unit
        const int base = lane & 32;
        float gi = __shfl(acc, base + 0);
        float gf = __shfl(acc, base + 8);
        float gg = __shfl(acc, base + 16);
        float go = __shfl(acc, base + 24);
        gi = 1.f / (1.f + __expf(-gi));
        gf = 1.f / (1.f + __expf(-gf));
        gg = 2.f / (1.f + __expf(-2.f * gg)) - 1.f;
        go = 1.f / (1.f + __expf(-go));
        c_state = gf * c_state + gi * gg;
        float hval = go * (2.f / (1.f + __expf(-2.f * c_state)) - 1.f);
        float hother = __shfl(hval, 32);   // partner unit's h
        if (lane == 0) {
            union { __half2 h; unsigned int u; } pk;
            pk.h = __halves2half2(__float2half_rn(hval), __float2half_rn(hother));
            unsigned long long val =
                ((unsigned long long)(unsigned)(t + 1) << 32) | pk.u;
            __hip_atomic_store(pub + (p << 9) + b * 8 + w, val,
                               __ATOMIC_RELAXED, SCOPE_AGENT);
        }
    }
}

// ---------------- final projection: out = h_final @ W_out^T + b_out ----------------
__global__ __launch_bounds__(256) void k_proj(unsigned long long* __restrict__ hfin,
                                              const float* __restrict__ Wout,
                                              const float* __restrict__ bout,
                                              float* __restrict__ out) {
    __shared__ float red[256];
    const int o = blockIdx.x, tid = threadIdx.x;
    const float* wr = Wout + (size_t)o * 1024;
    float acc = 0.f;
#pragma unroll
    for (int j = 0; j < 2; ++j) {
        int e = j * 256 + tid;
        unsigned long long v = __hip_atomic_load(hfin + e, __ATOMIC_RELAXED, SCOPE_AGENT);
        union { unsigned int u; __half2 h; } pk; pk.u = (unsigned)v;
        acc += __half2float(__low2half(pk.h)) * wr[2 * e] +
               __half2float(__high2half(pk.h)) * wr[2 * e + 1];
    }
    red[tid] = acc;
    __syncthreads();
    for (int s = 128; s > 0; s >>= 1) {
        if (tid < s) red[tid] += red[tid + s];
        __syncthreads();
    }
    if (tid == 0) out[o] = red[0] + bout[o];
}

extern "C" void kernel_launch(void* const* d_in, const int* in_sizes, int n_in,
                              void* d_out, int out_size, void* d_ws, size_t ws_size,
                              hipStream_t stream) {
    const float* input_seq = (const float*)d_in[0];
    const float* W_ih = (const float*)d_in[1];
    const float* W_hh = (const float*)d_in[2];
    const float* b_ih = (const float*)d_in[3];
    const float* b_hh = (const float*)d_in[4];
    const float* W_out = (const float*)d_in[5];
    const float* b_out = (const float*)d_in[6];
    float* out = (float*)d_out;

    char* ws = (char*)d_ws;
    unsigned long long* pub = (unsigned long long*)ws;             // [0, 8KB): [2][512] tagged h
    float* bias = (float*)(ws + 24576);                            // [24KB, 40KB)
    __half* Wih_h = (__half*)(ws + 65536);                         // 8MB
    __half* Whh_h = (__half*)(ws + 65536 + (size_t)8 * 1024 * 1024);   // 8MB
    __half* in_h  = (__half*)(ws + 65536 + (size_t)16 * 1024 * 1024);  // 16MB
    __half* xg    = (__half*)(ws + 65536 + (size_t)32 * 1024 * 1024);  // 64MB

    // clear tags each call (graph replay determinism)
    hipMemsetAsync(ws, 0, 8192, stream);

    k_f2h<<<8192, 256, 0, stream>>>(input_seq, in_h, 2 * 1024 * 1024);
    k_f2h<<<4096, 256, 0, stream>>>(W_ih, Wih_h, 1024 * 1024);
    k_f2h<<<4096, 256, 0, stream>>>(W_hh, Whh_h, 1024 * 1024);
    k_bias<<<16, 256, 0, stream>>>(b_ih, b_hh, bias);

    dim3 gg(64, 32);
    k_gemm_xg<<<gg, 256, 0, stream>>>(in_h, Wih_h, bias, xg);

    k_lstm<<<64, 512, 0, stream>>>(Whh_h, xg, pub);

    k_proj<<<1024, 256, 0, stream>>>(pub + 512, W_out, b_out, out);
}

// Round 4
// 20884.514 us; speedup vs baseline: 1.7824x; 1.0856x over previous
//
#include <hip/hip_runtime.h>
#include <hip/hip_fp16.h>

typedef _Float16 h2v __attribute__((ext_vector_type(2)));

__device__ __forceinline__ float fdot2(unsigned int a, unsigned int b, float c) {
    return __builtin_amdgcn_fdot2(__builtin_bit_cast(h2v, a),
                                  __builtin_bit_cast(h2v, b), c, false);
}

#define SCOPE_AGENT __HIP_MEMORY_SCOPE_AGENT

// ---------------- fp32 -> fp16 convert (vectorized x4) ----------------
__global__ __launch_bounds__(256) void k_f2h(const float* __restrict__ src,
                                             __half* __restrict__ dst, int n4) {
    int i = blockIdx.x * 256 + threadIdx.x;
    if (i >= n4) return;
    float4 v = ((const float4*)src)[i];
    union { __half2 h[2]; uint2 u; } o;
    o.h[0] = __halves2half2(__float2half_rn(v.x), __float2half_rn(v.y));
    o.h[1] = __halves2half2(__float2half_rn(v.z), __float2half_rn(v.w));
    ((uint2*)dst)[i] = o.u;
}

__global__ __launch_bounds__(256) void k_bias(const float* __restrict__ a,
                                              const float* __restrict__ b,
                                              float* __restrict__ o) {
    int i = blockIdx.x * 256 + threadIdx.x;
    if (i < 4096) o[i] = a[i] + b[i];
}

// ---------------- x_gates GEMM: C[8192][4096] = A[8192][1024] @ B[4096][1024]^T + bias ----
__global__ __launch_bounds__(256) void k_gemm_xg(const __half* __restrict__ A,
                                                 const __half* __restrict__ B,
                                                 const float* __restrict__ bias,
                                                 __half* __restrict__ C) {
    __shared__ unsigned int As[128][20];
    __shared__ unsigned int Bs[128][20];
    const int tid = threadIdx.x;
    const int tx = tid & 15, ty = tid >> 4;
    const int m0 = blockIdx.x * 128, n0 = blockIdx.y * 128;
    float acc[8][8];
#pragma unroll
    for (int i = 0; i < 8; ++i)
#pragma unroll
        for (int j = 0; j < 8; ++j) acc[i][j] = 0.f;
    const unsigned int* Ag = (const unsigned int*)(A + (size_t)m0 * 1024);
    const unsigned int* Bg = (const unsigned int*)(B + (size_t)n0 * 1024);
    for (int k0 = 0; k0 < 512; k0 += 16) {
        __syncthreads();
#pragma unroll
        for (int j = 0; j < 2; ++j) {
            int qd = j * 256 + tid;
            int row = qd >> 2;
            int c4 = (qd & 3) << 2;
            uint4 va = *(const uint4*)(Ag + (size_t)row * 512 + k0 + c4);
            uint4 vb = *(const uint4*)(Bg + (size_t)row * 512 + k0 + c4);
            *(uint4*)&As[row][c4] = va;
            *(uint4*)&Bs[row][c4] = vb;
        }
        __syncthreads();
#pragma unroll
        for (int k2 = 0; k2 < 16; k2 += 2) {
            unsigned int a0[8], a1[8], b0[8], b1[8];
#pragma unroll
            for (int i = 0; i < 8; ++i) {
                uint2 v = *(const uint2*)&As[ty + 16 * i][k2];
                a0[i] = v.x; a1[i] = v.y;
            }
#pragma unroll
            for (int j = 0; j < 8; ++j) {
                uint2 v = *(const uint2*)&Bs[tx + 16 * j][k2];
                b0[j] = v.x; b1[j] = v.y;
            }
#pragma unroll
            for (int i = 0; i < 8; ++i)
#pragma unroll
                for (int j = 0; j < 8; ++j) {
                    acc[i][j] = fdot2(a0[i], b0[j], acc[i][j]);
                    acc[i][j] = fdot2(a1[i], b1[j], acc[i][j]);
                }
        }
    }
#pragma unroll
    for (int i = 0; i < 8; ++i) {
        int row = m0 + ty + 16 * i;
#pragma unroll
        for (int j = 0; j < 8; ++j) {
            int col = n0 + tx + 16 * j;
            C[(size_t)row * 4096 + col] = __float2half_rn(acc[i][j] + bias[col]);
        }
    }
}

// ---------------- persistent LSTM recurrence ----------------
// 32 blocks x 512 threads (8 waves). Block b owns hidden units [32b,32b+32);
// wave w owns units 32b+4w..+4 (4 units x 4 gates = 16 rows).
// Lane (rho=lane>>2, cc=lane&3): row rho (gate=rho&3, unit=rho>>2), k-chunk cc
// of 256 halfs -> 32 uint4 = 128 VGPRs of W_hh per lane. No LDS weights.
// Handshake: tagged 8B word {tag=t+1 | h2} per entry, 512 entries; each lane
// polls ONE entry (single round trip: data rides with tag). One barrier/step.
__global__ __launch_bounds__(512, 1) void k_lstm(const __half* __restrict__ Whh,
                                                 const __half* __restrict__ xg,
                                                 unsigned long long* pub) { // [2][512]
    __shared__ unsigned int hs[2][544];    // 8 groups of 64 dwords, stride 68
    const int tid = threadIdx.x;
    const int b = blockIdx.x;              // 0..31
    const int w = tid >> 6, lane = tid & 63;
    const int rho = lane >> 2;             // 0..15: gate=rho&3, unit-local=rho>>2
    const int cc = lane & 3;               // k-chunk (256 halfs)
    const int grow = (rho & 3) * 1024 + b * 32 + 4 * w + (rho >> 2);
    uint4 wr[32];
#pragma unroll
    for (int i = 0; i < 32; ++i)
        wr[i] = *(const uint4*)(Whh + (size_t)grow * 1024 + cc * 256 + i * 8);
    const int soff = (tid >> 6) * 68 + (tid & 63);   // hs slot for entry tid
    float c_state = 0.f;
    __syncthreads();

    for (int t = 0; t < 8192; ++t) {
        // x_gates prefetch (independent of h; hides under the poll)
        float xv = __half2float(xg[(size_t)t * 4096 + grow]);
        unsigned int d = 0;
        if (t > 0) {
            const unsigned long long* src = pub + (((t - 1) & 1) << 9);
            unsigned long long v = __hip_atomic_load(src + tid, __ATOMIC_RELAXED, SCOPE_AGENT);
            while ((unsigned)(v >> 32) != (unsigned)t) {
                __builtin_amdgcn_s_sleep(1);
                v = __hip_atomic_load(src + tid, __ATOMIC_RELAXED, SCOPE_AGENT);
            }
            d = (unsigned)v;
        }
        const int p = t & 1;
        hs[p][soff] = d;
        __syncthreads();                   // the ONLY barrier per step
        float acc = 0.f;
        const unsigned int* hsp = &hs[p][cc * 136];
#pragma unroll
        for (int i = 0; i < 32; ++i) {
            uint4 h4 = *(const uint4*)(hsp + (i >> 4) * 68 + ((i & 15) << 2));
            acc = fdot2(wr[i].x, h4.x, acc);
            acc = fdot2(wr[i].y, h4.y, acc);
            acc = fdot2(wr[i].z, h4.z, acc);
            acc = fdot2(wr[i].w, h4.w, acc);
        }
        // reduce over the 4 k-chunks (lane bits 0..1)
        acc += __shfl_xor(acc, 1);
        acc += __shfl_xor(acc, 2);
        acc += xv;
        // gather the 4 gates of unit u = lane>>4 (row rho=4u+g at lane 16u+4g)
        const int base = lane & 48;
        float gi = __shfl(acc, base + 0);
        float gf = __shfl(acc, base + 4);
        float gg = __shfl(acc, base + 8);
        float go = __shfl(acc, base + 12);
        gi = 1.f / (1.f + __expf(-gi));
        gf = 1.f / (1.f + __expf(-gf));
        gg = 2.f / (1.f + __expf(-2.f * gg)) - 1.f;
        go = 1.f / (1.f + __expf(-go));
        c_state = gf * c_state + gi * gg;
        float hval = go * (2.f / (1.f + __expf(-2.f * c_state)) - 1.f);
        // pack: lane L<2 publishes units {2L, 2L+1} (h lives at lanes 16u)
        float ha = __shfl(hval, (lane & 1) << 5);          // unit 2L
        float hb = __shfl(hval, ((lane & 1) << 5) + 16);   // unit 2L+1
        if (lane < 2) {
            union { __half2 h; unsigned int u; } pk;
            pk.h = __halves2half2(__float2half_rn(ha), __float2half_rn(hb));
            unsigned long long val =
                ((unsigned long long)(unsigned)(t + 1) << 32) | pk.u;
            __hip_atomic_store(pub + (p << 9) + b * 16 + w * 2 + lane, val,
                               __ATOMIC_RELAXED, SCOPE_AGENT);
        }
    }
}

// ---------------- final projection: out = h_final @ W_out^T + b_out ----------------
__global__ __launch_bounds__(256) void k_proj(unsigned long long* __restrict__ hfin,
                                              const float* __restrict__ Wout,
                                              const float* __restrict__ bout,
                                              float* __restrict__ out) {
    __shared__ float red[256];
    const int o = blockIdx.x, tid = threadIdx.x;
    const float* wr = Wout + (size_t)o * 1024;
    float acc = 0.f;
#pragma unroll
    for (int j = 0; j < 2; ++j) {
        int e = j * 256 + tid;
        unsigned long long v = __hip_atomic_load(hfin + e, __ATOMIC_RELAXED, SCOPE_AGENT);
        union { unsigned int u; __half2 h; } pk; pk.u = (unsigned)v;
        acc += __half2float(__low2half(pk.h)) * wr[2 * e] +
               __half2float(__high2half(pk.h)) * wr[2 * e + 1];
    }
    red[tid] = acc;
    __syncthreads();
    for (int s = 128; s > 0; s >>= 1) {
        if (tid < s) red[tid] += red[tid + s];
        __syncthreads();
    }
    if (tid == 0) out[o] = red[0] + bout[o];
}

extern "C" void kernel_launch(void* const* d_in, const int* in_sizes, int n_in,
                              void* d_out, int out_size, void* d_ws, size_t ws_size,
                              hipStream_t stream) {
    const float* input_seq = (const float*)d_in[0];
    const float* W_ih = (const float*)d_in[1];
    const float* W_hh = (const float*)d_in[2];
    const float* b_ih = (const float*)d_in[3];
    const float* b_hh = (const float*)d_in[4];
    const float* W_out = (const float*)d_in[5];
    const float* b_out = (const float*)d_in[6];
    float* out = (float*)d_out;

    char* ws = (char*)d_ws;
    unsigned long long* pub = (unsigned long long*)ws;             // [0, 8KB): [2][512] tagged h
    float* bias = (float*)(ws + 24576);                            // [24KB, 40KB)
    __half* Wih_h = (__half*)(ws + 65536);                         // 8MB
    __half* Whh_h = (__half*)(ws + 65536 + (size_t)8 * 1024 * 1024);   // 8MB
    __half* in_h  = (__half*)(ws + 65536 + (size_t)16 * 1024 * 1024);  // 16MB
    __half* xg    = (__half*)(ws + 65536 + (size_t)32 * 1024 * 1024);  // 64MB

    // clear tags each call (graph replay determinism)
    hipMemsetAsync(ws, 0, 8192, stream);

    k_f2h<<<8192, 256, 0, stream>>>(input_seq, in_h, 2 * 1024 * 1024);
    k_f2h<<<4096, 256, 0, stream>>>(W_ih, Wih_h, 1024 * 1024);
    k_f2h<<<4096, 256, 0, stream>>>(W_hh, Whh_h, 1024 * 1024);
    k_bias<<<16, 256, 0, stream>>>(b_ih, b_hh, bias);

    dim3 gg(64, 32);
    k_gemm_xg<<<gg, 256, 0, stream>>>(in_h, Wih_h, bias, xg);

    k_lstm<<<32, 512, 0, stream>>>(Whh_h, xg, pub);

    k_proj<<<1024, 256, 0, stream>>>(pub + 512, W_out, b_out, out);
}

// Round 5
// 20702.669 us; speedup vs baseline: 1.7981x; 1.0088x over previous
//
#include <hip/hip_runtime.h>
#include <hip/hip_fp16.h>

typedef _Float16 h2v __attribute__((ext_vector_type(2)));

__device__ __forceinline__ float fdot2(unsigned int a, unsigned int b, float c) {
    return __builtin_amdgcn_fdot2(__builtin_bit_cast(h2v, a),
                                  __builtin_bit_cast(h2v, b), c, false);
}

#define SCOPE_SYS __HIP_MEMORY_SCOPE_SYSTEM

// ---------------- fp32 -> fp16 convert (vectorized x4) ----------------
__global__ __launch_bounds__(256) void k_f2h(const float* __restrict__ src,
                                             __half* __restrict__ dst, int n4) {
    int i = blockIdx.x * 256 + threadIdx.x;
    if (i >= n4) return;
    float4 v = ((const float4*)src)[i];
    union { __half2 h[2]; uint2 u; } o;
    o.h[0] = __halves2half2(__float2half_rn(v.x), __float2half_rn(v.y));
    o.h[1] = __halves2half2(__float2half_rn(v.z), __float2half_rn(v.w));
    ((uint2*)dst)[i] = o.u;
}

__global__ __launch_bounds__(256) void k_bias(const float* __restrict__ a,
                                              const float* __restrict__ b,
                                              float* __restrict__ o) {
    int i = blockIdx.x * 256 + threadIdx.x;
    if (i < 4096) o[i] = a[i] + b[i];
}

// ---------------- x_gates GEMM: C[8192][4096] = A[8192][1024] @ B[4096][1024]^T + bias ----
__global__ __launch_bounds__(256) void k_gemm_xg(const __half* __restrict__ A,
                                                 const __half* __restrict__ B,
                                                 const float* __restrict__ bias,
                                                 __half* __restrict__ C) {
    __shared__ unsigned int As[128][20];
    __shared__ unsigned int Bs[128][20];
    const int tid = threadIdx.x;
    const int tx = tid & 15, ty = tid >> 4;
    const int m0 = blockIdx.x * 128, n0 = blockIdx.y * 128;
    float acc[8][8];
#pragma unroll
    for (int i = 0; i < 8; ++i)
#pragma unroll
        for (int j = 0; j < 8; ++j) acc[i][j] = 0.f;
    const unsigned int* Ag = (const unsigned int*)(A + (size_t)m0 * 1024);
    const unsigned int* Bg = (const unsigned int*)(B + (size_t)n0 * 1024);
    for (int k0 = 0; k0 < 512; k0 += 16) {
        __syncthreads();
#pragma unroll
        for (int j = 0; j < 2; ++j) {
            int qd = j * 256 + tid;
            int row = qd >> 2;
            int c4 = (qd & 3) << 2;
            uint4 va = *(const uint4*)(Ag + (size_t)row * 512 + k0 + c4);
            uint4 vb = *(const uint4*)(Bg + (size_t)row * 512 + k0 + c4);
            *(uint4*)&As[row][c4] = va;
            *(uint4*)&Bs[row][c4] = vb;
        }
        __syncthreads();
#pragma unroll
        for (int k2 = 0; k2 < 16; k2 += 2) {
            unsigned int a0[8], a1[8], b0[8], b1[8];
#pragma unroll
            for (int i = 0; i < 8; ++i) {
                uint2 v = *(const uint2*)&As[ty + 16 * i][k2];
                a0[i] = v.x; a1[i] = v.y;
            }
#pragma unroll
            for (int j = 0; j < 8; ++j) {
                uint2 v = *(const uint2*)&Bs[tx + 16 * j][k2];
                b0[j] = v.x; b1[j] = v.y;
            }
#pragma unroll
            for (int i = 0; i < 8; ++i)
#pragma unroll
                for (int j = 0; j < 8; ++j) {
                    acc[i][j] = fdot2(a0[i], b0[j], acc[i][j]);
                    acc[i][j] = fdot2(a1[i], b1[j], acc[i][j]);
                }
        }
    }
#pragma unroll
    for (int i = 0; i < 8; ++i) {
        int row = m0 + ty + 16 * i;
#pragma unroll
        for (int j = 0; j < 8; ++j) {
            int col = n0 + tx + 16 * j;
            C[(size_t)row * 4096 + col] = __float2half_rn(acc[i][j] + bias[col]);
        }
    }
}

// ---------------- persistent LSTM recurrence ----------------
// 32 blocks x 512 threads (8 waves). Block b owns hidden units [32b,32b+32);
// wave w owns units 32b+4w..+4 (4 units x 4 gates = 16 rows).
// Lane (rho=lane>>2, cc=lane&3): row rho (gate=rho&3, unit=rho>>2), k-chunk cc
// of 256 halfs -> 32 uint4 = 128 VGPRs of W_hh per lane. No LDS weights.
// Handshake: SYSTEM-scope (sc0 sc1 -> Infinity Cache meeting point, avoids
// cross-XCD dirty-L2 probes) 4B tagged words {tag16|h16}, one per hidden unit,
// published directly by the unit's owner lane. Each poller lane reads ONE 8B
// word = two tagged halfs = the h2 dword it stages. Tight spin, no sleep.
__global__ __launch_bounds__(512, 1) void k_lstm(const __half* __restrict__ Whh,
                                                 const __half* __restrict__ xg,
                                                 unsigned int* pub) { // [2][1024]
    __shared__ unsigned int hs[2][544];    // 8 groups of 64 dwords, stride 68
    const int tid = threadIdx.x;
    const int b = blockIdx.x;              // 0..31
    const int w = tid >> 6, lane = tid & 63;
    const int rho = lane >> 2;             // 0..15: gate=rho&3, unit-local=rho>>2
    const int cc = lane & 3;               // k-chunk (256 halfs)
    const int grow = (rho & 3) * 1024 + b * 32 + 4 * w + (rho >> 2);
    uint4 wr[32];
#pragma unroll
    for (int i = 0; i < 32; ++i)
        wr[i] = *(const uint4*)(Whh + (size_t)grow * 1024 + cc * 256 + i * 8);
    const int soff = (tid >> 6) * 68 + (tid & 63);   // hs slot for h2-dword tid
    const int upub = b * 32 + w * 4 + (lane >> 4);   // unit this lane may publish
    float c_state = 0.f;
    __syncthreads();

    for (int t = 0; t < 8192; ++t) {
        // x_gates prefetch (independent of h; overlaps the poll)
        float xv = __half2float(xg[(size_t)t * 4096 + grow]);
        unsigned int d = 0;
        if (t > 0) {
            const unsigned long long* src =
                (const unsigned long long*)(pub + (((t - 1) & 1) << 10)) + tid;
            const unsigned tt = (unsigned)t;
            unsigned long long v = __hip_atomic_load(src, __ATOMIC_RELAXED, SCOPE_SYS);
            unsigned lo = (unsigned)v, hi = (unsigned)(v >> 32);
            while ((lo >> 16) != tt || (hi >> 16) != tt) {
                v = __hip_atomic_load(src, __ATOMIC_RELAXED, SCOPE_SYS);
                lo = (unsigned)v; hi = (unsigned)(v >> 32);
            }
            d = (lo & 0xffffu) | (hi << 16);
        }
        const int p = t & 1;
        hs[p][soff] = d;
        __syncthreads();                   // the ONLY barrier per step
        float acc = 0.f;
        const unsigned int* hsp = &hs[p][cc * 136];
#pragma unroll
        for (int i = 0; i < 32; ++i) {
            uint4 h4 = *(const uint4*)(hsp + (i >> 4) * 68 + ((i & 15) << 2));
            acc = fdot2(wr[i].x, h4.x, acc);
            acc = fdot2(wr[i].y, h4.y, acc);
            acc = fdot2(wr[i].z, h4.z, acc);
            acc = fdot2(wr[i].w, h4.w, acc);
        }
        // reduce over the 4 k-chunks (lane bits 0..1)
        acc += __shfl_xor(acc, 1);
        acc += __shfl_xor(acc, 2);
        acc += xv;
        // gather the 4 gates of unit u = lane>>4 (row rho=4u+g at lane 16u+4g)
        const int base = lane & 48;
        float gi = __shfl(acc, base + 0);
        float gf = __shfl(acc, base + 4);
        float gg = __shfl(acc, base + 8);
        float go = __shfl(acc, base + 12);
        gi = 1.f / (1.f + __expf(-gi));
        gf = 1.f / (1.f + __expf(-gf));
        gg = 2.f / (1.f + __expf(-2.f * gg)) - 1.f;
        go = 1.f / (1.f + __expf(-go));
        c_state = gf * c_state + gi * gg;
        float hval = go * (2.f / (1.f + __expf(-2.f * c_state)) - 1.f);
        // publish: every 16-lane unit-group's lane 0 stores its own unit's h
        if ((lane & 15) == 0) {
            unsigned val = ((unsigned)(t + 1) << 16) |
                           (unsigned)__half_as_ushort(__float2half_rn(hval));
            __hip_atomic_store(pub + (p << 10) + upub, val,
                               __ATOMIC_RELAXED, SCOPE_SYS);
        }
    }
}

// ---------------- final projection: out = h_final @ W_out^T + b_out ----------------
__global__ __launch_bounds__(256) void k_proj(const unsigned int* __restrict__ hfin,
                                              const float* __restrict__ Wout,
                                              const float* __restrict__ bout,
                                              float* __restrict__ out) {
    __shared__ float red[256];
    const int o = blockIdx.x, tid = threadIdx.x;
    const float* wr = Wout + (size_t)o * 1024;
    float acc = 0.f;
#pragma unroll
    for (int j = 0; j < 4; ++j) {
        int e = j * 256 + tid;
        unsigned v = hfin[e];              // {tag16 | h16}
        acc += __half2float(__ushort_as_half((unsigned short)(v & 0xffffu))) * wr[e];
    }
    red[tid] = acc;
    __syncthreads();
    for (int s = 128; s > 0; s >>= 1) {
        if (tid < s) red[tid] += red[tid + s];
        __syncthreads();
    }
    if (tid == 0) out[o] = red[0] + bout[o];
}

extern "C" void kernel_launch(void* const* d_in, const int* in_sizes, int n_in,
                              void* d_out, int out_size, void* d_ws, size_t ws_size,
                              hipStream_t stream) {
    const float* input_seq = (const float*)d_in[0];
    const float* W_ih = (const float*)d_in[1];
    const float* W_hh = (const float*)d_in[2];
    const float* b_ih = (const float*)d_in[3];
    const float* b_hh = (const float*)d_in[4];
    const float* W_out = (const float*)d_in[5];
    const float* b_out = (const float*)d_in[6];
    float* out = (float*)d_out;

    char* ws = (char*)d_ws;
    unsigned int* pub = (unsigned int*)ws;                         // [0, 8KB): [2][1024] tagged h
    float* bias = (float*)(ws + 24576);                            // [24KB, 40KB)
    __half* Wih_h = (__half*)(ws + 65536);                         // 8MB
    __half* Whh_h = (__half*)(ws + 65536 + (size_t)8 * 1024 * 1024);   // 8MB
    __half* in_h  = (__half*)(ws + 65536 + (size_t)16 * 1024 * 1024);  // 16MB
    __half* xg    = (__half*)(ws + 65536 + (size_t)32 * 1024 * 1024);  // 64MB

    // clear tags each call (graph replay determinism)
    hipMemsetAsync(ws, 0, 8192, stream);

    k_f2h<<<8192, 256, 0, stream>>>(input_seq, in_h, 2 * 1024 * 1024);
    k_f2h<<<4096, 256, 0, stream>>>(W_ih, Wih_h, 1024 * 1024);
    k_f2h<<<4096, 256, 0, stream>>>(W_hh, Whh_h, 1024 * 1024);
    k_bias<<<16, 256, 0, stream>>>(b_ih, b_hh, bias);

    dim3 gg(64, 32);
    k_gemm_xg<<<gg, 256, 0, stream>>>(in_h, Wih_h, bias, xg);

    k_lstm<<<32, 512, 0, stream>>>(Whh_h, xg, pub);

    k_proj<<<1024, 256, 0, stream>>>(pub + 1024, W_out, b_out, out);
}